// Round 2
// baseline (408.527 us; speedup 1.0000x reference)
//
#include <hip/hip_runtime.h>
#include <hip/hip_bf16.h>
#include <stdint.h>

// S5 layer: L=16384, H=1024, P=1024. fp32 in/out. Round-9:
//   - GEMM K-loop de-barriered: all 24 ds_read_b128 per K-tile issued up
//     front (order pinned), counted lgkmcnt(12/8/0) waits between MFMA
//     clusters instead of per-phase lgkmcnt(0)+s_barrier. Only 2 barriers
//     per K-tile (buffer-overwrite fence + stage-confirm fence). Waves slip
//     within the tile -> DS latency hides under partner wave's MFMA.
//   - everything else from round-8 kept: 256x256 tile, BK=64, 8 waves,
//     dbuf LDS, counted vmcnt(8) global prefetch, XOR bank swizzle via
//     pre-swizzled global src, XCD swizzle, setprio around MFMA,
//     MODE1 fused chunk aggregates, MODE2 fused D-residual epilogue.

#define L_SEQ 16384
#define H_DIM 1024
#define P_DIM 1024
#define NCH   256
#define TCH   64

typedef __bf16 bf16x8 __attribute__((ext_vector_type(8)));
typedef float  floatx4 __attribute__((ext_vector_type(4)));
using bf16 = __hip_bfloat16;

__device__ __forceinline__ void gld_lds16(const void* g, void* l) {
    __builtin_amdgcn_global_load_lds(
        (const __attribute__((address_space(1))) uint32_t*)g,
        (__attribute__((address_space(3))) uint32_t*)l, 16, 0, 0);
}

__device__ __forceinline__ float lo_bf(uint32_t v) { return __uint_as_float(v << 16); }
__device__ __forceinline__ float hi_bf(uint32_t v) { return __uint_as_float(v & 0xffff0000u); }
__device__ __forceinline__ uint32_t pack_bf(float r, float i) {
    bf16 rb = __float2bfloat16(r), ib = __float2bfloat16(i);
    return ((uint32_t)(*(uint16_t*)&ib) << 16) | (uint32_t)(*(uint16_t*)&rb);
}

__device__ __forceinline__ float rd(const void* p, size_t i, int f) {
    return f ? ((const float*)p)[i]
             : __bfloat162float(((const bf16*)p)[i]);
}

// per-block dtype self-detect (fp32 halfwords read as bf16 show |x|>=128)
__device__ __forceinline__ int detect_f32(const uint16_t* u) {
    __shared__ int cnt;
    if (threadIdx.x == 0) cnt = 0;
    __syncthreads();
    int c = 0;
    #pragma unroll
    for (int i = 0; i < 8; ++i) {
        int e = (u[threadIdx.x * 8 + i] >> 7) & 0xFF;
        c += (e >= 134);
    }
    if (c) atomicAdd(&cnt, c);
    __syncthreads();
    return cnt > 32;
}

// ---------------------------------------------------------------- convert u
__global__ void convert_u(const void* __restrict__ uin, bf16* __restrict__ ub) {
    const int f = detect_f32((const uint16_t*)uin);
    const size_t g = (size_t)blockIdx.x * 256 + threadIdx.x;
    if (f) {
        const float4* s = (const float4*)uin + g * 2;
        float4 a = s[0], b = s[1];
        alignas(16) bf16 t[8] = {
            __float2bfloat16(a.x), __float2bfloat16(a.y),
            __float2bfloat16(a.z), __float2bfloat16(a.w),
            __float2bfloat16(b.x), __float2bfloat16(b.y),
            __float2bfloat16(b.z), __float2bfloat16(b.w)};
        ((uint4*)ub)[g] = *(const uint4*)t;
    } else {
        ((uint4*)ub)[g] = ((const uint4*)uin)[g];
    }
}

// ---------------------------------------------------------------- prep (fused)
__global__ void prep_all(const void* __restrict__ u,
                         const void* __restrict__ Lre, const void* __restrict__ Lim,
                         const void* __restrict__ lstep, const void* __restrict__ B,
                         const void* __restrict__ C, const void* __restrict__ D,
                         bf16* __restrict__ W1t, bf16* __restrict__ W2t,
                         float* __restrict__ d_f,
                         float2* __restrict__ lam, float2* __restrict__ lamT) {
    const int f = detect_f32((const uint16_t*)u);
    const int p = blockIdx.x;
    float lr = fminf(rd(Lre, p, f), -1e-4f);
    float li = rd(Lim, p, f);
    float s  = expf(rd(lstep, p, f));
    float ea = expf(lr * s);
    float lbr = ea * cosf(li * s), lbi = ea * sinf(li * s);   // lambda_bar
    float dr = lbr - 1.0f, di = lbi;
    float den = lr * lr + li * li;
    float cr = (dr * lr + di * li) / den;                     // (lb-1)/Lambda
    float ci = (di * lr - dr * li) / den;
    if (threadIdx.x == 0) {
        lam[p] = make_float2(lbr, lbi);
        float tr = lbr, ti = lbi;                             // lambda_bar^64
        #pragma unroll
        for (int q = 0; q < 6; ++q) {
            float nr = tr * tr - ti * ti, ni = 2.0f * tr * ti;
            tr = nr; ti = ni;
        }
        lamT[p] = make_float2(tr, ti);
        d_f[p] = rd(D, p, f);
    }
    for (int h = threadIdx.x; h < H_DIM; h += blockDim.x) {
        size_t base = ((size_t)p * H_DIM + h) * 2;
        float br = rd(B, base + 0, f);
        float bi = rd(B, base + 1, f);
        W1t[(size_t)(2 * p)     * H_DIM + h] = __float2bfloat16(cr * br - ci * bi);
        W1t[(size_t)(2 * p + 1) * H_DIM + h] = __float2bfloat16(cr * bi + ci * br);
    }
    const int h = blockIdx.x;
    for (int q = threadIdx.x; q < P_DIM; q += blockDim.x) {
        size_t base = ((size_t)h * P_DIM + q) * 2;
        W2t[(size_t)h * (2 * P_DIM) + 2 * q]     = __float2bfloat16( 2.0f * rd(C, base + 0, f));
        W2t[(size_t)h * (2 * P_DIM) + 2 * q + 1] = __float2bfloat16(-2.0f * rd(C, base + 1, f));
    }
}

// ---------------------------------------------------------------- GEMM 256x256
// A(M,K) bf16 rm, Bt(N,K) bf16 rm. 256x256 tile, BK=64, 8 waves (2Mx4N),
// dbuf LDS, counted vmcnt + counted lgkmcnt (no intra-tile barriers),
// granule XOR swizzle via pre-swizzled global_load_lds source, setprio
// around MFMA clusters, XCD swizzle.
// MODE 1: OutBF bf16 + fused chunk aggregates (register-only weights).
// MODE 2: OutF fp32 = acc + U*Dvec, nontemporal.

#define SB0 __builtin_amdgcn_sched_barrier(0)

#define STAGE(b, t) do {                                                      \
    const int k0_ = (t) * 64;                                                 \
    _Pragma("unroll")                                                         \
    for (int q_ = 0; q_ < 4; ++q_) {                                          \
        const int row_ = q_ * 64 + srow;                                      \
        const int g_   = sg ^ (row_ & 7);                                     \
        gld_lds16(A  + (size_t)(bm + row_) * K + k0_ + g_ * 8,                \
                  sA + (b) * 32768 + q_ * 8192 + wave * 1024);                \
        gld_lds16(Bt + (size_t)(bn + row_) * K + k0_ + g_ * 8,                \
                  sB + (b) * 32768 + q_ * 8192 + wave * 1024);                \
    } } while (0)

// load 4 A-fragment rows (mh half) into dst[4][2]
#define LDF_A(dst, b, mh) do {                                                \
    _Pragma("unroll")                                                         \
    for (int mi_ = 0; mi_ < 4; ++mi_) {                                       \
        const int row_ = wm + ((mh) * 4 + mi_) * 16 + fr;                     \
        _Pragma("unroll")                                                     \
        for (int ks_ = 0; ks_ < 2; ++ks_) {                                   \
            const int ch_ = (ks_ * 4 + kq) ^ (row_ & 7);                      \
            dst[mi_][ks_] = *(const bf16x8*)(sA + (b) * 32768 + row_ * 128 + ch_ * 16); \
        } } } while (0)

// load 2 B-fragment rows (nh half) into dst[2][2]
#define LDF_B(dst, b, nh) do {                                                \
    _Pragma("unroll")                                                         \
    for (int ni_ = 0; ni_ < 2; ++ni_) {                                       \
        const int row_ = wn + ((nh) * 2 + ni_) * 16 + fr;                     \
        _Pragma("unroll")                                                     \
        for (int ks_ = 0; ks_ < 2; ++ks_) {                                   \
            const int ch_ = (ks_ * 4 + kq) ^ (row_ & 7);                      \
            dst[ni_][ks_] = *(const bf16x8*)(sB + (b) * 32768 + row_ * 128 + ch_ * 16); \
        } } } while (0)

#define MMA(afv, bfv, mh, nh) do {                                            \
    _Pragma("unroll")                                                         \
    for (int mi_ = 0; mi_ < 4; ++mi_)                                         \
        _Pragma("unroll")                                                     \
        for (int ni_ = 0; ni_ < 2; ++ni_)                                     \
            _Pragma("unroll")                                                 \
            for (int ks_ = 0; ks_ < 2; ++ks_)                                 \
                acc[(mh) * 4 + mi_][(nh) * 2 + ni_] =                         \
                    __builtin_amdgcn_mfma_f32_16x16x32_bf16(                  \
                        afv[mi_][ks_], bfv[ni_][ks_],                         \
                        acc[(mh) * 4 + mi_][(nh) * 2 + ni_], 0, 0, 0);        \
} while (0)

template <int N, int K, int MODE>
__global__ __launch_bounds__(512, 2) void gemm256(
    const bf16* __restrict__ A, const bf16* __restrict__ Bt,
    bf16* __restrict__ OutBF, float* __restrict__ OutF,
    const bf16* __restrict__ U, const float* __restrict__ Dvec,
    const float2* __restrict__ lam, float2* __restrict__ aggp) {
    constexpr int NXB = N / 256;
    constexpr int KT  = K / 64;
    __shared__ alignas(16) uint8_t sA[2 * 32768];   // [buf][256 rows][128 B]
    __shared__ alignas(16) uint8_t sB[2 * 32768];

    const int tid  = threadIdx.x;
    const int wave = tid >> 6;
    const int lane = tid & 63;
    const int bid  = blockIdx.x;
    const int xr   = bid & 7;
    const int jj   = bid >> 3;
    const int bx   = jj % NXB;
    const int by   = (jj / NXB) * 8 + xr;
    const int bm   = by * 256, bn = bx * 256;
    const int wm   = (wave >> 2) * 128, wn = (wave & 3) * 64;

    floatx4 acc[8][4] = {};

    const int fr   = lane & 15;
    const int kq   = lane >> 4;        // 0..3
    const int srow = tid >> 3;         // 0..63
    const int sg   = tid & 7;

    // prologue: stage tiles 0,1; wait tile 0 (tile-1's 8 loads stay in flight)
    STAGE(0, 0);
    STAGE(1, 1);
    asm volatile("s_waitcnt vmcnt(8)" ::: "memory");
    SB0;
    __builtin_amdgcn_s_barrier();

    bf16x8 afA[4][2], afB[4][2], bf0[2][2], bf1[2][2];

    #pragma unroll 2
    for (int t = 0; t < KT; ++t) {
        const int cur = t & 1;
        // issue all 24 ds_read_b128 for this K-tile, order pinned:
        // afA(8), bf0(4), bf1(4), afB(8). DS completes in-order per wave.
        LDF_A(afA, cur, 0); SB0;
        LDF_B(bf0, cur, 0); SB0;
        LDF_B(bf1, cur, 1); SB0;
        LDF_A(afB, cur, 1); SB0;
        // afA+bf0 done (12 outstanding: bf1 + afB)
        asm volatile("s_waitcnt lgkmcnt(12)" ::: "memory");
        SB0;
        __builtin_amdgcn_s_setprio(1);
        MMA(afA, bf0, 0, 0);
        __builtin_amdgcn_s_setprio(0);
        // bf1 done (8 outstanding: afB)
        asm volatile("s_waitcnt lgkmcnt(8)" ::: "memory");
        SB0;
        __builtin_amdgcn_s_setprio(1);
        MMA(afA, bf1, 0, 1);
        __builtin_amdgcn_s_setprio(0);
        // afB done
        asm volatile("s_waitcnt lgkmcnt(0)" ::: "memory");
        SB0;
        __builtin_amdgcn_s_setprio(1);
        MMA(afB, bf0, 1, 0);
        MMA(afB, bf1, 1, 1);
        __builtin_amdgcn_s_setprio(0);
        // all waves done reading buf[cur] -> safe to overwrite with tile t+2
        __builtin_amdgcn_s_barrier();
        if (t + 2 < KT) {
            STAGE(cur, t + 2);
            asm volatile("s_waitcnt vmcnt(8)" ::: "memory");  // tile t+1 landed
        } else {
            asm volatile("s_waitcnt vmcnt(0)" ::: "memory");  // epilogue drain
        }
        SB0;
        __builtin_amdgcn_s_barrier();
    }

    // ---- C write ----
    const int col0  = bn + wn + fr;
    const int rbase = bm + wm + kq * 4;
    #pragma unroll
    for (int mi = 0; mi < 8; ++mi) {
        #pragma unroll
        for (int rr = 0; rr < 4; ++rr) {
            const int row = rbase + mi * 16 + rr;
            #pragma unroll
            for (int ni = 0; ni < 4; ++ni) {
                const int c = col0 + ni * 16;
                float v = acc[mi][ni][rr];
                if (MODE == 2) {
                    float uu = __bfloat162float(U[(size_t)row * H_DIM + c]);
                    __builtin_nontemporal_store(v + uu * Dvec[c],
                                                &OutF[(size_t)row * N + c]);
                } else {
                    OutBF[(size_t)row * N + c] = __float2bfloat16(v);
                }
            }
        }
    }

    if (MODE == 1) {
        // ---- fused phase1: agg_cg(p) = sum_t lam_p^(63-t) * Bu_t(p) ----
        // Wave spans 2 chunks of 64 rows (half h: mi 4h..4h+3). Within a
        // chunk t = mi2*16 + kq*4 + rr; register-only weights: w starts at
        // lam^(12-4kq), *= lam per t-step, *= lam^12 between mi2 groups.
        // Even lane holds re, odd lane im (interleaved cols).
        const int par = fr & 1;
        const int cg0 = (bm + wm) >> 6;
        #pragma unroll
        for (int ni = 0; ni < 4; ++ni) {
            const int ql = (wn + ni * 16 + (fr & ~1)) >> 1;   // 0..127
            const float2 lb = lam[(bn >> 1) + ql];
            const float l1r = lb.x, l1i = lb.y;
            const float l2r = l1r * l1r - l1i * l1i, l2i = 2.f * l1r * l1i;
            const float l4r = l2r * l2r - l2i * l2i, l4i = 2.f * l2r * l2i;
            const float l8r = l4r * l4r - l4i * l4i, l8i = 2.f * l4r * l4i;
            const float l12r = l8r * l4r - l8i * l4i;
            const float l12i = l8r * l4i + l8i * l4r;
            #pragma unroll
            for (int h = 0; h < 2; ++h) {
                float wr_, wi_;                     // lam^(12-4kq)
                if      (kq == 0) { wr_ = l12r; wi_ = l12i; }
                else if (kq == 1) { wr_ = l8r;  wi_ = l8i;  }
                else if (kq == 2) { wr_ = l4r;  wi_ = l4i;  }
                else              { wr_ = 1.f;  wi_ = 0.f;  }
                float s = 0.f;
                #pragma unroll
                for (int mi2 = 3; mi2 >= 0; --mi2) {
                    #pragma unroll
                    for (int rr = 3; rr >= 0; --rr) {
                        float own  = acc[h * 4 + mi2][ni][rr];
                        float part = __shfl_xor(own, 1);
                        s += wr_ * own + (par ? wi_ : -wi_) * part;
                        float nr = wr_ * l1r - wi_ * l1i;
                        float nI = wr_ * l1i + wi_ * l1r;
                        wr_ = nr; wi_ = nI;
                    }
                    float nr = wr_ * l12r - wi_ * l12i;
                    float nI = wr_ * l12i + wi_ * l12r;
                    wr_ = nr; wi_ = nI;
                }
                s += __shfl_xor(s, 16);             // reduce over kq
                s += __shfl_xor(s, 32);
                float other = __shfl_xor(s, 1);     // partner component
                if (kq == 0 && par == 0)
                    aggp[(size_t)(cg0 + h) * P_DIM + (bn >> 1) + ql] =
                        make_float2(s, other);
            }
        }
    }
}

// ---------------------------------------------------------------- scan
// phase2: wave-parallel carries. 1 wave per state; lane j owns chunks 4j..4j+3.
__global__ void scan_phase2p(const float2* __restrict__ agg,
                             const float2* __restrict__ lamT,
                             float2* __restrict__ carry) {
    const int w = threadIdx.x >> 6;
    const int j = threadIdx.x & 63;
    const int p = blockIdx.x * 4 + w;
    const float2 A = lamT[p];                               // lam^64
    float b2r = A.x * A.x - A.y * A.y, b2i = 2.f * A.x * A.y;
    float Br = b2r * b2r - b2i * b2i, Bi = 2.f * b2r * b2i; // lam^256
    float2 a[4];
    #pragma unroll
    for (int k = 0; k < 4; ++k) a[k] = agg[(size_t)(4 * j + k) * P_DIM + p];
    float xr = 0.f, xi = 0.f;
    #pragma unroll
    for (int k = 0; k < 4; ++k) {
        float nr = A.x * xr - A.y * xi + a[k].x;
        float ni = A.x * xi + A.y * xr + a[k].y;
        xr = nr; xi = ni;
    }
    float cr = Br, ci = Bi, vr = xr, vi = xi;
    #pragma unroll
    for (int d = 1; d < 64; d <<= 1) {
        float pvr = __shfl_up(vr, d), pvi = __shfl_up(vi, d);
        float pcr = __shfl_up(cr, d), pci = __shfl_up(ci, d);
        if (j >= d) {
            float nvr = cr * pvr - ci * pvi + vr;
            float nvi = cr * pvi + ci * pvr + vi;
            float ncr = cr * pcr - ci * pci;
            float nci = cr * pci + ci * pcr;
            vr = nvr; vi = nvi; cr = ncr; ci = nci;
        }
    }
    float sr = __shfl_up(vr, 1), si = __shfl_up(vi, 1);     // exclusive seed
    if (j == 0) { sr = 0.f; si = 0.f; }
    #pragma unroll
    for (int k = 0; k < 4; ++k) {
        carry[(size_t)(4 * j + k) * P_DIM + p] = make_float2(sr, si);
        float nr = A.x * sr - A.y * si + a[k].x;
        float ni = A.x * si + A.y * sr + a[k].y;
        sr = nr; si = ni;
    }
}

__global__ void scan_phase3(uint32_t* __restrict__ BuX,             // in-place
                            const float2* __restrict__ lam,
                            const float2* __restrict__ carry) {
    const int p = blockIdx.y * 256 + threadIdx.x;
    const int c = blockIdx.x;
    const float2 lb = lam[p];
    const float2 c0 = carry[(size_t)c * P_DIM + p];
    float xr = c0.x, xi = c0.y;
    uint32_t* b = BuX + (size_t)c * TCH * P_DIM + p;
    #pragma unroll 4
    for (int j = 0; j < TCH; ++j) {
        uint32_t v = *b;
        float nr = lb.x * xr - lb.y * xi + lo_bf(v);
        float ni = lb.x * xi + lb.y * xr + hi_bf(v);
        xr = nr; xi = ni;
        *b = pack_bf(xr, xi);
        b += P_DIM;
    }
}

// ---------------------------------------------------------------- launch
extern "C" void kernel_launch(void* const* d_in, const int* in_sizes, int n_in,
                              void* d_out, int out_size, void* d_ws, size_t ws_size,
                              hipStream_t stream) {
    float* out = (float*)d_out;  // (L,H) fp32

    char* w = (char*)d_ws;
    w += 256;
    float2* lam   = (float2*)w;  w += (size_t)P_DIM * 8;
    float2* lamT  = (float2*)w;  w += (size_t)P_DIM * 8;
    float*  d_f   = (float*)w;   w += (size_t)H_DIM * 4;
    float2* agg   = (float2*)w;  w += (size_t)NCH * P_DIM * 8;       // 2 MB
    float2* carry = (float2*)w;  w += (size_t)NCH * P_DIM * 8;       // 2 MB
    bf16*   W1t   = (bf16*)w;    w += (size_t)2 * P_DIM * H_DIM * 2; // 4 MB
    bf16*   W2t   = (bf16*)w;    w += (size_t)H_DIM * 2 * P_DIM * 2; // 4 MB
    bf16*   ub    = (bf16*)w;    w += (size_t)L_SEQ * H_DIM * 2;     // 33.5 MB
    bf16*   Xbuf  = (bf16*)w;                                        // 67 MB

    convert_u<<<(L_SEQ * H_DIM / 8) / 256, 256, 0, stream>>>(d_in[0], ub);
    prep_all<<<P_DIM, 256, 0, stream>>>(d_in[0], d_in[1], d_in[2], d_in[6],
                                        d_in[3], d_in[4], d_in[5],
                                        W1t, W2t, d_f, lam, lamT);

    // Bu(L,2P) = ub @ W1t^T  (interleaved cols) + fused chunk aggregates
    gemm256<2 * P_DIM, H_DIM, 1><<<(2 * P_DIM / 256) * (L_SEQ / 256), 512, 0, stream>>>(
        ub, W1t, Xbuf, nullptr, nullptr, nullptr, lam, agg);

    scan_phase2p<<<P_DIM / 4, 256, 0, stream>>>(agg, lamT, carry);
    scan_phase3<<<dim3(NCH, P_DIM / 256), 256, 0, stream>>>(
        (uint32_t*)Xbuf, lam, carry);

    // out = X @ W2t^T + ub*D
    gemm256<H_DIM, 2 * P_DIM, 2><<<(H_DIM / 256) * (L_SEQ / 256), 512, 0, stream>>>(
        Xbuf, W2t, nullptr, out, ub, d_f, nullptr, nullptr);
}

// Round 3
// 324.100 us; speedup vs baseline: 1.2605x; 1.2605x over previous
//
#include <hip/hip_runtime.h>
#include <hip/hip_bf16.h>
#include <stdint.h>

// S5 layer: L=16384, H=1024, P=1024. fp32 in/out. Round-10:
//   - Round-9 post-mortem: de-barriered schedule spilled (24 live frags =
//     96 VGPR + 128 acc blew the 256-reg / 2-waves-per-SIMD cap; FETCH+12MB
//     WRITE+24MB scratch traffic). Round-10 keeps the de-barriered counted
//     waits but with round-8's 12-fragment in-place live set (48 VGPR):
//     phases 0-2 have NO barriers (per-wave lgkmcnt(0) only; SIMD-partner
//     wave's MFMA hides the DS drain). Phase 3: lgkm drain -> barrier ->
//     STAGE(t+2) issued -> final MFMA cluster overlaps the stage flight ->
//     vmcnt(8) -> barrier. 2 barriers/tile vs round-8's 6.
//   - everything else kept: 256x256 tile, BK=64, 8 waves 2Mx4N, dbuf LDS,
//     XOR bank swizzle via pre-swizzled global src, XCD swizzle, setprio,
//     MODE1 fused chunk aggregates, MODE2 fused D-residual epilogue.

#define L_SEQ 16384
#define H_DIM 1024
#define P_DIM 1024
#define NCH   256
#define TCH   64

typedef __bf16 bf16x8 __attribute__((ext_vector_type(8)));
typedef float  floatx4 __attribute__((ext_vector_type(4)));
using bf16 = __hip_bfloat16;

__device__ __forceinline__ void gld_lds16(const void* g, void* l) {
    __builtin_amdgcn_global_load_lds(
        (const __attribute__((address_space(1))) uint32_t*)g,
        (__attribute__((address_space(3))) uint32_t*)l, 16, 0, 0);
}

__device__ __forceinline__ float lo_bf(uint32_t v) { return __uint_as_float(v << 16); }
__device__ __forceinline__ float hi_bf(uint32_t v) { return __uint_as_float(v & 0xffff0000u); }
__device__ __forceinline__ uint32_t pack_bf(float r, float i) {
    bf16 rb = __float2bfloat16(r), ib = __float2bfloat16(i);
    return ((uint32_t)(*(uint16_t*)&ib) << 16) | (uint32_t)(*(uint16_t*)&rb);
}

__device__ __forceinline__ float rd(const void* p, size_t i, int f) {
    return f ? ((const float*)p)[i]
             : __bfloat162float(((const bf16*)p)[i]);
}

// per-block dtype self-detect (fp32 halfwords read as bf16 show |x|>=128)
__device__ __forceinline__ int detect_f32(const uint16_t* u) {
    __shared__ int cnt;
    if (threadIdx.x == 0) cnt = 0;
    __syncthreads();
    int c = 0;
    #pragma unroll
    for (int i = 0; i < 8; ++i) {
        int e = (u[threadIdx.x * 8 + i] >> 7) & 0xFF;
        c += (e >= 134);
    }
    if (c) atomicAdd(&cnt, c);
    __syncthreads();
    return cnt > 32;
}

// ---------------------------------------------------------------- convert u
__global__ void convert_u(const void* __restrict__ uin, bf16* __restrict__ ub) {
    const int f = detect_f32((const uint16_t*)uin);
    const size_t g = (size_t)blockIdx.x * 256 + threadIdx.x;
    if (f) {
        const float4* s = (const float4*)uin + g * 2;
        float4 a = s[0], b = s[1];
        alignas(16) bf16 t[8] = {
            __float2bfloat16(a.x), __float2bfloat16(a.y),
            __float2bfloat16(a.z), __float2bfloat16(a.w),
            __float2bfloat16(b.x), __float2bfloat16(b.y),
            __float2bfloat16(b.z), __float2bfloat16(b.w)};
        ((uint4*)ub)[g] = *(const uint4*)t;
    } else {
        ((uint4*)ub)[g] = ((const uint4*)uin)[g];
    }
}

// ---------------------------------------------------------------- prep (fused)
__global__ void prep_all(const void* __restrict__ u,
                         const void* __restrict__ Lre, const void* __restrict__ Lim,
                         const void* __restrict__ lstep, const void* __restrict__ B,
                         const void* __restrict__ C, const void* __restrict__ D,
                         bf16* __restrict__ W1t, bf16* __restrict__ W2t,
                         float* __restrict__ d_f,
                         float2* __restrict__ lam, float2* __restrict__ lamT) {
    const int f = detect_f32((const uint16_t*)u);
    const int p = blockIdx.x;
    float lr = fminf(rd(Lre, p, f), -1e-4f);
    float li = rd(Lim, p, f);
    float s  = expf(rd(lstep, p, f));
    float ea = expf(lr * s);
    float lbr = ea * cosf(li * s), lbi = ea * sinf(li * s);   // lambda_bar
    float dr = lbr - 1.0f, di = lbi;
    float den = lr * lr + li * li;
    float cr = (dr * lr + di * li) / den;                     // (lb-1)/Lambda
    float ci = (di * lr - dr * li) / den;
    if (threadIdx.x == 0) {
        lam[p] = make_float2(lbr, lbi);
        float tr = lbr, ti = lbi;                             // lambda_bar^64
        #pragma unroll
        for (int q = 0; q < 6; ++q) {
            float nr = tr * tr - ti * ti, ni = 2.0f * tr * ti;
            tr = nr; ti = ni;
        }
        lamT[p] = make_float2(tr, ti);
        d_f[p] = rd(D, p, f);
    }
    for (int h = threadIdx.x; h < H_DIM; h += blockDim.x) {
        size_t base = ((size_t)p * H_DIM + h) * 2;
        float br = rd(B, base + 0, f);
        float bi = rd(B, base + 1, f);
        W1t[(size_t)(2 * p)     * H_DIM + h] = __float2bfloat16(cr * br - ci * bi);
        W1t[(size_t)(2 * p + 1) * H_DIM + h] = __float2bfloat16(cr * bi + ci * br);
    }
    const int h = blockIdx.x;
    for (int q = threadIdx.x; q < P_DIM; q += blockDim.x) {
        size_t base = ((size_t)h * P_DIM + q) * 2;
        W2t[(size_t)h * (2 * P_DIM) + 2 * q]     = __float2bfloat16( 2.0f * rd(C, base + 0, f));
        W2t[(size_t)h * (2 * P_DIM) + 2 * q + 1] = __float2bfloat16(-2.0f * rd(C, base + 1, f));
    }
}

// ---------------------------------------------------------------- GEMM 256x256
// A(M,K) bf16 rm, Bt(N,K) bf16 rm. 256x256 tile, BK=64, 8 waves (2Mx4N),
// dbuf LDS, 12-frag in-place live set, per-phase lgkmcnt(0) (no intra-tile
// barriers), stage overlapped with last MFMA cluster, counted vmcnt(8),
// granule XOR swizzle via pre-swizzled global_load_lds source, setprio,
// XCD swizzle.
// MODE 1: OutBF bf16 + fused chunk aggregates (register-only weights).
// MODE 2: OutF fp32 = acc + U*Dvec, nontemporal.

#define SB0 __builtin_amdgcn_sched_barrier(0)

#define STAGE(b, t) do {                                                      \
    const int k0_ = (t) * 64;                                                 \
    _Pragma("unroll")                                                         \
    for (int q_ = 0; q_ < 4; ++q_) {                                          \
        const int row_ = q_ * 64 + srow;                                      \
        const int g_   = sg ^ (row_ & 7);                                     \
        gld_lds16(A  + (size_t)(bm + row_) * K + k0_ + g_ * 8,                \
                  sA + (b) * 32768 + q_ * 8192 + wave * 1024);                \
        gld_lds16(Bt + (size_t)(bn + row_) * K + k0_ + g_ * 8,                \
                  sB + (b) * 32768 + q_ * 8192 + wave * 1024);                \
    } } while (0)

// load 4 A-fragment rows (mh half) into af[4][2] (in-place overwrite)
#define LDA(b, mh) do {                                                       \
    _Pragma("unroll")                                                         \
    for (int mi_ = 0; mi_ < 4; ++mi_) {                                       \
        const int row_ = wm + ((mh) * 4 + mi_) * 16 + fr;                     \
        _Pragma("unroll")                                                     \
        for (int ks_ = 0; ks_ < 2; ++ks_) {                                   \
            const int ch_ = (ks_ * 4 + kq) ^ (row_ & 7);                      \
            af[mi_][ks_] = *(const bf16x8*)(sA + (b) * 32768 + row_ * 128 + ch_ * 16); \
        } } } while (0)

// load 2 B-fragment rows (nh half) into bfr[2][2] (in-place overwrite)
#define LDB(b, nh) do {                                                       \
    _Pragma("unroll")                                                         \
    for (int ni_ = 0; ni_ < 2; ++ni_) {                                       \
        const int row_ = wn + ((nh) * 2 + ni_) * 16 + fr;                     \
        _Pragma("unroll")                                                     \
        for (int ks_ = 0; ks_ < 2; ++ks_) {                                   \
            const int ch_ = (ks_ * 4 + kq) ^ (row_ & 7);                      \
            bfr[ni_][ks_] = *(const bf16x8*)(sB + (b) * 32768 + row_ * 128 + ch_ * 16); \
        } } } while (0)

#define WAIT_DS do {                                                          \
    asm volatile("s_waitcnt lgkmcnt(0)" ::: "memory");                        \
    SB0;                                                                      \
} while (0)

#define MMA(mh, nh) do {                                                      \
    __builtin_amdgcn_s_setprio(1);                                            \
    _Pragma("unroll")                                                         \
    for (int mi_ = 0; mi_ < 4; ++mi_)                                         \
        _Pragma("unroll")                                                     \
        for (int ni_ = 0; ni_ < 2; ++ni_)                                     \
            _Pragma("unroll")                                                 \
            for (int ks_ = 0; ks_ < 2; ++ks_)                                 \
                acc[(mh) * 4 + mi_][(nh) * 2 + ni_] =                         \
                    __builtin_amdgcn_mfma_f32_16x16x32_bf16(                  \
                        af[mi_][ks_], bfr[ni_][ks_],                          \
                        acc[(mh) * 4 + mi_][(nh) * 2 + ni_], 0, 0, 0);        \
    __builtin_amdgcn_s_setprio(0);                                            \
} while (0)

template <int N, int K, int MODE>
__global__ __launch_bounds__(512, 2) void gemm256(
    const bf16* __restrict__ A, const bf16* __restrict__ Bt,
    bf16* __restrict__ OutBF, float* __restrict__ OutF,
    const bf16* __restrict__ U, const float* __restrict__ Dvec,
    const float2* __restrict__ lam, float2* __restrict__ aggp) {
    constexpr int NXB = N / 256;
    constexpr int KT  = K / 64;
    __shared__ alignas(16) uint8_t sA[2 * 32768];   // [buf][256 rows][128 B]
    __shared__ alignas(16) uint8_t sB[2 * 32768];

    const int tid  = threadIdx.x;
    const int wave = tid >> 6;
    const int lane = tid & 63;
    const int bid  = blockIdx.x;
    const int xr   = bid & 7;
    const int jj   = bid >> 3;
    const int bx   = jj % NXB;
    const int by   = (jj / NXB) * 8 + xr;
    const int bm   = by * 256, bn = bx * 256;
    const int wm   = (wave >> 2) * 128, wn = (wave & 3) * 64;

    floatx4 acc[8][4] = {};

    const int fr   = lane & 15;
    const int kq   = lane >> 4;        // 0..3
    const int srow = tid >> 3;         // 0..63
    const int sg   = tid & 7;

    // prologue: stage tiles 0,1; wait tile 0 (tile-1's 8 loads stay in flight)
    STAGE(0, 0);
    STAGE(1, 1);
    asm volatile("s_waitcnt vmcnt(8)" ::: "memory");
    SB0;
    __builtin_amdgcn_s_barrier();

    bf16x8 af[4][2], bfr[2][2];

    #pragma unroll 2
    for (int t = 0; t < KT; ++t) {
        const int cur = t & 1;
        // phase 0: (mh0, nh0) — 12 ds_read_b128, own-wave drain, no barrier
        LDA(cur, 0); LDB(cur, 0);
        WAIT_DS;
        MMA(0, 0);
        // phase 1: (mh0, nh1) — reuse af, 4 reads
        LDB(cur, 1);
        WAIT_DS;
        MMA(0, 1);
        // phase 2: (mh1, nh1) — reuse bfr, 8 reads
        LDA(cur, 1);
        WAIT_DS;
        MMA(1, 1);
        // phase 3: (mh1, nh0) — 4 reads; these are the LAST reads of buf[cur]
        LDB(cur, 0);
        WAIT_DS;
        __builtin_amdgcn_s_barrier();       // all waves done reading buf[cur]
        if (t + 2 < KT) STAGE(cur, t + 2);  // overwrite ok; flies under MFMA
        MMA(1, 0);
        if (t + 2 < KT) {
            asm volatile("s_waitcnt vmcnt(8)" ::: "memory");  // t+1 landed
        } else {
            asm volatile("s_waitcnt vmcnt(0)" ::: "memory");  // epilogue drain
        }
        SB0;
        __builtin_amdgcn_s_barrier();       // buf[cur^1] ready for all waves
    }

    // ---- C write ----
    const int col0  = bn + wn + fr;
    const int rbase = bm + wm + kq * 4;
    #pragma unroll
    for (int mi = 0; mi < 8; ++mi) {
        #pragma unroll
        for (int rr = 0; rr < 4; ++rr) {
            const int row = rbase + mi * 16 + rr;
            #pragma unroll
            for (int ni = 0; ni < 4; ++ni) {
                const int c = col0 + ni * 16;
                float v = acc[mi][ni][rr];
                if (MODE == 2) {
                    float uu = __bfloat162float(U[(size_t)row * H_DIM + c]);
                    __builtin_nontemporal_store(v + uu * Dvec[c],
                                                &OutF[(size_t)row * N + c]);
                } else {
                    OutBF[(size_t)row * N + c] = __float2bfloat16(v);
                }
            }
        }
    }

    if (MODE == 1) {
        // ---- fused phase1: agg_cg(p) = sum_t lam_p^(63-t) * Bu_t(p) ----
        // Wave spans 2 chunks of 64 rows (half h: mi 4h..4h+3). Within a
        // chunk t = mi2*16 + kq*4 + rr; register-only weights: w starts at
        // lam^(12-4kq), *= lam per t-step, *= lam^12 between mi2 groups.
        // Even lane holds re, odd lane im (interleaved cols).
        const int par = fr & 1;
        const int cg0 = (bm + wm) >> 6;
        #pragma unroll
        for (int ni = 0; ni < 4; ++ni) {
            const int ql = (wn + ni * 16 + (fr & ~1)) >> 1;   // 0..127
            const float2 lb = lam[(bn >> 1) + ql];
            const float l1r = lb.x, l1i = lb.y;
            const float l2r = l1r * l1r - l1i * l1i, l2i = 2.f * l1r * l1i;
            const float l4r = l2r * l2r - l2i * l2i, l4i = 2.f * l2r * l2i;
            const float l8r = l4r * l4r - l4i * l4i, l8i = 2.f * l4r * l4i;
            const float l12r = l8r * l4r - l8i * l4i;
            const float l12i = l8r * l4i + l8i * l4r;
            #pragma unroll
            for (int h = 0; h < 2; ++h) {
                float wr_, wi_;                     // lam^(12-4kq)
                if      (kq == 0) { wr_ = l12r; wi_ = l12i; }
                else if (kq == 1) { wr_ = l8r;  wi_ = l8i;  }
                else if (kq == 2) { wr_ = l4r;  wi_ = l4i;  }
                else              { wr_ = 1.f;  wi_ = 0.f;  }
                float s = 0.f;
                #pragma unroll
                for (int mi2 = 3; mi2 >= 0; --mi2) {
                    #pragma unroll
                    for (int rr = 3; rr >= 0; --rr) {
                        float own  = acc[h * 4 + mi2][ni][rr];
                        float part = __shfl_xor(own, 1);
                        s += wr_ * own + (par ? wi_ : -wi_) * part;
                        float nr = wr_ * l1r - wi_ * l1i;
                        float nI = wr_ * l1i + wi_ * l1r;
                        wr_ = nr; wi_ = nI;
                    }
                    float nr = wr_ * l12r - wi_ * l12i;
                    float nI = wr_ * l12i + wi_ * l12r;
                    wr_ = nr; wi_ = nI;
                }
                s += __shfl_xor(s, 16);             // reduce over kq
                s += __shfl_xor(s, 32);
                float other = __shfl_xor(s, 1);     // partner component
                if (kq == 0 && par == 0)
                    aggp[(size_t)(cg0 + h) * P_DIM + (bn >> 1) + ql] =
                        make_float2(s, other);
            }
        }
    }
}

// ---------------------------------------------------------------- scan
// phase2: wave-parallel carries. 1 wave per state; lane j owns chunks 4j..4j+3.
__global__ void scan_phase2p(const float2* __restrict__ agg,
                             const float2* __restrict__ lamT,
                             float2* __restrict__ carry) {
    const int w = threadIdx.x >> 6;
    const int j = threadIdx.x & 63;
    const int p = blockIdx.x * 4 + w;
    const float2 A = lamT[p];                               // lam^64
    float b2r = A.x * A.x - A.y * A.y, b2i = 2.f * A.x * A.y;
    float Br = b2r * b2r - b2i * b2i, Bi = 2.f * b2r * b2i; // lam^256
    float2 a[4];
    #pragma unroll
    for (int k = 0; k < 4; ++k) a[k] = agg[(size_t)(4 * j + k) * P_DIM + p];
    float xr = 0.f, xi = 0.f;
    #pragma unroll
    for (int k = 0; k < 4; ++k) {
        float nr = A.x * xr - A.y * xi + a[k].x;
        float ni = A.x * xi + A.y * xr + a[k].y;
        xr = nr; xi = ni;
    }
    float cr = Br, ci = Bi, vr = xr, vi = xi;
    #pragma unroll
    for (int d = 1; d < 64; d <<= 1) {
        float pvr = __shfl_up(vr, d), pvi = __shfl_up(vi, d);
        float pcr = __shfl_up(cr, d), pci = __shfl_up(ci, d);
        if (j >= d) {
            float nvr = cr * pvr - ci * pvi + vr;
            float nvi = cr * pvi + ci * pvr + vi;
            float ncr = cr * pcr - ci * pci;
            float nci = cr * pci + ci * pcr;
            vr = nvr; vi = nvi; cr = ncr; ci = nci;
        }
    }
    float sr = __shfl_up(vr, 1), si = __shfl_up(vi, 1);     // exclusive seed
    if (j == 0) { sr = 0.f; si = 0.f; }
    #pragma unroll
    for (int k = 0; k < 4; ++k) {
        carry[(size_t)(4 * j + k) * P_DIM + p] = make_float2(sr, si);
        float nr = A.x * sr - A.y * si + a[k].x;
        float ni = A.x * si + A.y * sr + a[k].y;
        sr = nr; si = ni;
    }
}

__global__ void scan_phase3(uint32_t* __restrict__ BuX,             // in-place
                            const float2* __restrict__ lam,
                            const float2* __restrict__ carry) {
    const int p = blockIdx.y * 256 + threadIdx.x;
    const int c = blockIdx.x;
    const float2 lb = lam[p];
    const float2 c0 = carry[(size_t)c * P_DIM + p];
    float xr = c0.x, xi = c0.y;
    uint32_t* b = BuX + (size_t)c * TCH * P_DIM + p;
    #pragma unroll 4
    for (int j = 0; j < TCH; ++j) {
        uint32_t v = *b;
        float nr = lb.x * xr - lb.y * xi + lo_bf(v);
        float ni = lb.x * xi + lb.y * xr + hi_bf(v);
        xr = nr; xi = ni;
        *b = pack_bf(xr, xi);
        b += P_DIM;
    }
}

// ---------------------------------------------------------------- launch
extern "C" void kernel_launch(void* const* d_in, const int* in_sizes, int n_in,
                              void* d_out, int out_size, void* d_ws, size_t ws_size,
                              hipStream_t stream) {
    float* out = (float*)d_out;  // (L,H) fp32

    char* w = (char*)d_ws;
    w += 256;
    float2* lam   = (float2*)w;  w += (size_t)P_DIM * 8;
    float2* lamT  = (float2*)w;  w += (size_t)P_DIM * 8;
    float*  d_f   = (float*)w;   w += (size_t)H_DIM * 4;
    float2* agg   = (float2*)w;  w += (size_t)NCH * P_DIM * 8;       // 2 MB
    float2* carry = (float2*)w;  w += (size_t)NCH * P_DIM * 8;       // 2 MB
    bf16*   W1t   = (bf16*)w;    w += (size_t)2 * P_DIM * H_DIM * 2; // 4 MB
    bf16*   W2t   = (bf16*)w;    w += (size_t)H_DIM * 2 * P_DIM * 2; // 4 MB
    bf16*   ub    = (bf16*)w;    w += (size_t)L_SEQ * H_DIM * 2;     // 33.5 MB
    bf16*   Xbuf  = (bf16*)w;                                        // 67 MB

    convert_u<<<(L_SEQ * H_DIM / 8) / 256, 256, 0, stream>>>(d_in[0], ub);
    prep_all<<<P_DIM, 256, 0, stream>>>(d_in[0], d_in[1], d_in[2], d_in[6],
                                        d_in[3], d_in[4], d_in[5],
                                        W1t, W2t, d_f, lam, lamT);

    // Bu(L,2P) = ub @ W1t^T  (interleaved cols) + fused chunk aggregates
    gemm256<2 * P_DIM, H_DIM, 1><<<(2 * P_DIM / 256) * (L_SEQ / 256), 512, 0, stream>>>(
        ub, W1t, Xbuf, nullptr, nullptr, nullptr, lam, agg);

    scan_phase2p<<<P_DIM / 4, 256, 0, stream>>>(agg, lamT, carry);
    scan_phase3<<<dim3(NCH, P_DIM / 256), 256, 0, stream>>>(
        (uint32_t*)Xbuf, lam, carry);

    // out = X @ W2t^T + ub*D
    gemm256<H_DIM, 2 * P_DIM, 2><<<(H_DIM / 256) * (L_SEQ / 256), 512, 0, stream>>>(
        Xbuf, W2t, nullptr, out, ub, d_f, nullptr, nullptr);
}

// Round 4
// 322.187 us; speedup vs baseline: 1.2680x; 1.0059x over previous
//
#include <hip/hip_runtime.h>
#include <hip/hip_bf16.h>
#include <stdint.h>

// S5 layer: L=16384, H=1024, P=1024. fp32 in/out. Round-11:
//   - Round-10 post-mortem: MfmaUtil 31 / VALU 24 / HBM 17 / conflicts 0 ->
//     exposed latency, not BW. 1 block/CU (128KiB LDS) x 8 waves = only
//     2 waves/SIMD; barriers keep the pair in lockstep so lgkm/vmcnt drains
//     have no partner coverage. acc[8][4]=128 regs forbids deeper per-wave
//     pipelining (round-9 spill).
//   - Round-11: 16 waves/block (1024 thr), wave tile 64x64, acc[4][4]=64
//     regs -> fits 128-reg cap at 4 waves/SIMD (launch_bounds(1024,4)).
//     4x the SIMD-partner coverage for every wait. Phases: 8-MFMA clusters
//     (2Mx2Nx2ks), same no-barrier counted lgkm waits, STAGE overlapped
//     with last cluster, counted vmcnt(4).
//   - kept: 256x256 block, BK=64, dbuf LDS, XOR bank swizzle via
//     pre-swizzled global src, XCD swizzle, setprio, MODE1 fused chunk
//     aggregates (wave = exactly one 64-row chunk now), MODE2 fused
//     D-residual epilogue, scan kernels, convert/prep.

#define L_SEQ 16384
#define H_DIM 1024
#define P_DIM 1024
#define NCH   256
#define TCH   64

typedef __bf16 bf16x8 __attribute__((ext_vector_type(8)));
typedef float  floatx4 __attribute__((ext_vector_type(4)));
using bf16 = __hip_bfloat16;

__device__ __forceinline__ void gld_lds16(const void* g, void* l) {
    __builtin_amdgcn_global_load_lds(
        (const __attribute__((address_space(1))) uint32_t*)g,
        (__attribute__((address_space(3))) uint32_t*)l, 16, 0, 0);
}

__device__ __forceinline__ float lo_bf(uint32_t v) { return __uint_as_float(v << 16); }
__device__ __forceinline__ float hi_bf(uint32_t v) { return __uint_as_float(v & 0xffff0000u); }
__device__ __forceinline__ uint32_t pack_bf(float r, float i) {
    bf16 rb = __float2bfloat16(r), ib = __float2bfloat16(i);
    return ((uint32_t)(*(uint16_t*)&ib) << 16) | (uint32_t)(*(uint16_t*)&rb);
}

__device__ __forceinline__ float rd(const void* p, size_t i, int f) {
    return f ? ((const float*)p)[i]
             : __bfloat162float(((const bf16*)p)[i]);
}

// per-block dtype self-detect (fp32 halfwords read as bf16 show |x|>=128)
__device__ __forceinline__ int detect_f32(const uint16_t* u) {
    __shared__ int cnt;
    if (threadIdx.x == 0) cnt = 0;
    __syncthreads();
    int c = 0;
    #pragma unroll
    for (int i = 0; i < 8; ++i) {
        int e = (u[threadIdx.x * 8 + i] >> 7) & 0xFF;
        c += (e >= 134);
    }
    if (c) atomicAdd(&cnt, c);
    __syncthreads();
    return cnt > 32;
}

// ---------------------------------------------------------------- convert u
__global__ void convert_u(const void* __restrict__ uin, bf16* __restrict__ ub) {
    const int f = detect_f32((const uint16_t*)uin);
    const size_t g = (size_t)blockIdx.x * 256 + threadIdx.x;
    if (f) {
        const float4* s = (const float4*)uin + g * 2;
        float4 a = s[0], b = s[1];
        alignas(16) bf16 t[8] = {
            __float2bfloat16(a.x), __float2bfloat16(a.y),
            __float2bfloat16(a.z), __float2bfloat16(a.w),
            __float2bfloat16(b.x), __float2bfloat16(b.y),
            __float2bfloat16(b.z), __float2bfloat16(b.w)};
        ((uint4*)ub)[g] = *(const uint4*)t;
    } else {
        ((uint4*)ub)[g] = ((const uint4*)uin)[g];
    }
}

// ---------------------------------------------------------------- prep (fused)
__global__ void prep_all(const void* __restrict__ u,
                         const void* __restrict__ Lre, const void* __restrict__ Lim,
                         const void* __restrict__ lstep, const void* __restrict__ B,
                         const void* __restrict__ C, const void* __restrict__ D,
                         bf16* __restrict__ W1t, bf16* __restrict__ W2t,
                         float* __restrict__ d_f,
                         float2* __restrict__ lam, float2* __restrict__ lamT) {
    const int f = detect_f32((const uint16_t*)u);
    const int p = blockIdx.x;
    float lr = fminf(rd(Lre, p, f), -1e-4f);
    float li = rd(Lim, p, f);
    float s  = expf(rd(lstep, p, f));
    float ea = expf(lr * s);
    float lbr = ea * cosf(li * s), lbi = ea * sinf(li * s);   // lambda_bar
    float dr = lbr - 1.0f, di = lbi;
    float den = lr * lr + li * li;
    float cr = (dr * lr + di * li) / den;                     // (lb-1)/Lambda
    float ci = (di * lr - dr * li) / den;
    if (threadIdx.x == 0) {
        lam[p] = make_float2(lbr, lbi);
        float tr = lbr, ti = lbi;                             // lambda_bar^64
        #pragma unroll
        for (int q = 0; q < 6; ++q) {
            float nr = tr * tr - ti * ti, ni = 2.0f * tr * ti;
            tr = nr; ti = ni;
        }
        lamT[p] = make_float2(tr, ti);
        d_f[p] = rd(D, p, f);
    }
    for (int h = threadIdx.x; h < H_DIM; h += blockDim.x) {
        size_t base = ((size_t)p * H_DIM + h) * 2;
        float br = rd(B, base + 0, f);
        float bi = rd(B, base + 1, f);
        W1t[(size_t)(2 * p)     * H_DIM + h] = __float2bfloat16(cr * br - ci * bi);
        W1t[(size_t)(2 * p + 1) * H_DIM + h] = __float2bfloat16(cr * bi + ci * br);
    }
    const int h = blockIdx.x;
    for (int q = threadIdx.x; q < P_DIM; q += blockDim.x) {
        size_t base = ((size_t)h * P_DIM + q) * 2;
        W2t[(size_t)h * (2 * P_DIM) + 2 * q]     = __float2bfloat16( 2.0f * rd(C, base + 0, f));
        W2t[(size_t)h * (2 * P_DIM) + 2 * q + 1] = __float2bfloat16(-2.0f * rd(C, base + 1, f));
    }
}

// ---------------------------------------------------------------- GEMM 256x256
// A(M,K) bf16 rm, Bt(N,K) bf16 rm. 256x256 block, BK=64, 16 waves (4Mx4N),
// wave tile 64x64, acc[4][4]=64 regs, 4 waves/SIMD. dbuf LDS, per-phase
// counted lgkm waits (no intra-tile barriers), STAGE overlapped with last
// MFMA cluster, counted vmcnt(4), XOR bank swizzle via pre-swizzled
// global_load_lds source, setprio, XCD swizzle.
// MODE 1: OutBF bf16 + fused chunk aggregates (wave = one 64-row chunk).
// MODE 2: OutF fp32 = acc + U*Dvec, nontemporal.

#define SB0 __builtin_amdgcn_sched_barrier(0)

#define STAGE(b, t) do {                                                      \
    const int k0_ = (t) * 64;                                                 \
    _Pragma("unroll")                                                         \
    for (int q_ = 0; q_ < 2; ++q_) {                                          \
        const int row_ = q_ * 128 + srow;                                     \
        const int g_   = sg ^ (row_ & 7);                                     \
        gld_lds16(A  + (size_t)(bm + row_) * K + k0_ + g_ * 8,                \
                  sA + (b) * 32768 + q_ * 16384 + wave * 1024);               \
        gld_lds16(Bt + (size_t)(bn + row_) * K + k0_ + g_ * 8,                \
                  sB + (b) * 32768 + q_ * 16384 + wave * 1024);               \
    } } while (0)

// load 2 A-fragment rows (mh half) into af[2][2] (in-place overwrite)
#define LDA(b, mh) do {                                                      \
    _Pragma("unroll")                                                        \
    for (int mi_ = 0; mi_ < 2; ++mi_) {                                      \
        const int row_ = wm + (mh) * 32 + mi_ * 16 + fr;                     \
        _Pragma("unroll")                                                    \
        for (int ks_ = 0; ks_ < 2; ++ks_) {                                  \
            const int ch_ = (ks_ * 4 + kq) ^ (row_ & 7);                     \
            af[mi_][ks_] = *(const bf16x8*)(sA + (b) * 32768 + row_ * 128 + ch_ * 16); \
        } } } while (0)

// load 2 B-fragment rows (nh half) into bfr[2][2] (in-place overwrite)
#define LDB(b, nh) do {                                                      \
    _Pragma("unroll")                                                        \
    for (int ni_ = 0; ni_ < 2; ++ni_) {                                      \
        const int row_ = wn + (nh) * 32 + ni_ * 16 + fr;                     \
        _Pragma("unroll")                                                    \
        for (int ks_ = 0; ks_ < 2; ++ks_) {                                  \
            const int ch_ = (ks_ * 4 + kq) ^ (row_ & 7);                     \
            bfr[ni_][ks_] = *(const bf16x8*)(sB + (b) * 32768 + row_ * 128 + ch_ * 16); \
        } } } while (0)

#define WAIT_DS do {                                                          \
    asm volatile("s_waitcnt lgkmcnt(0)" ::: "memory");                        \
    SB0;                                                                      \
} while (0)

#define MMA(mh, nh) do {                                                      \
    __builtin_amdgcn_s_setprio(1);                                            \
    _Pragma("unroll")                                                         \
    for (int mi_ = 0; mi_ < 2; ++mi_)                                         \
        _Pragma("unroll")                                                     \
        for (int ni_ = 0; ni_ < 2; ++ni_)                                     \
            _Pragma("unroll")                                                 \
            for (int ks_ = 0; ks_ < 2; ++ks_)                                 \
                acc[(mh) * 2 + mi_][(nh) * 2 + ni_] =                         \
                    __builtin_amdgcn_mfma_f32_16x16x32_bf16(                  \
                        af[mi_][ks_], bfr[ni_][ks_],                          \
                        acc[(mh) * 2 + mi_][(nh) * 2 + ni_], 0, 0, 0);        \
    __builtin_amdgcn_s_setprio(0);                                            \
} while (0)

template <int N, int K, int MODE>
__global__ __launch_bounds__(1024, 4) void gemm256(
    const bf16* __restrict__ A, const bf16* __restrict__ Bt,
    bf16* __restrict__ OutBF, float* __restrict__ OutF,
    const bf16* __restrict__ U, const float* __restrict__ Dvec,
    const float2* __restrict__ lam, float2* __restrict__ aggp) {
    constexpr int NXB = N / 256;
    constexpr int KT  = K / 64;
    __shared__ alignas(16) uint8_t sA[2 * 32768];   // [buf][256 rows][128 B]
    __shared__ alignas(16) uint8_t sB[2 * 32768];

    const int tid  = threadIdx.x;
    const int wave = tid >> 6;
    const int lane = tid & 63;
    const int bid  = blockIdx.x;
    const int xr   = bid & 7;
    const int jj   = bid >> 3;
    const int bx   = jj % NXB;
    const int by   = (jj / NXB) * 8 + xr;
    const int bm   = by * 256, bn = bx * 256;
    const int wm   = (wave >> 2) * 64, wn = (wave & 3) * 64;

    floatx4 acc[4][4] = {};

    const int fr   = lane & 15;
    const int kq   = lane >> 4;        // 0..3
    const int srow = tid >> 3;         // 0..127
    const int sg   = tid & 7;

    // prologue: stage tiles 0,1; wait tile 0 (tile-1's 4 loads stay in flight)
    STAGE(0, 0);
    STAGE(1, 1);
    asm volatile("s_waitcnt vmcnt(4)" ::: "memory");
    SB0;
    __builtin_amdgcn_s_barrier();

    bf16x8 af[2][2], bfr[2][2];

    #pragma unroll 2
    for (int t = 0; t < KT; ++t) {
        const int cur = t & 1;
        // phase 0: (mh0, nh0) — 8 ds_read_b128, own-wave drain, no barrier
        LDA(cur, 0); LDB(cur, 0);
        WAIT_DS;
        MMA(0, 0);
        // phase 1: (mh0, nh1) — reuse af, 4 reads
        LDB(cur, 1);
        WAIT_DS;
        MMA(0, 1);
        // phase 2: (mh1, nh1) — reuse bfr, 4 reads
        LDA(cur, 1);
        WAIT_DS;
        MMA(1, 1);
        // phase 3: (mh1, nh0) — 4 reads; these are the LAST reads of buf[cur]
        LDB(cur, 0);
        WAIT_DS;
        __builtin_amdgcn_s_barrier();       // all waves done reading buf[cur]
        if (t + 2 < KT) STAGE(cur, t + 2);  // overwrite ok; flies under MFMA
        MMA(1, 0);
        if (t + 2 < KT) {
            asm volatile("s_waitcnt vmcnt(4)" ::: "memory");  // t+1 landed
        } else {
            asm volatile("s_waitcnt vmcnt(0)" ::: "memory");  // epilogue drain
        }
        SB0;
        __builtin_amdgcn_s_barrier();       // buf[cur^1] ready for all waves
    }

    // ---- C write ----
    const int col0  = bn + wn + fr;
    const int rbase = bm + wm + kq * 4;
    #pragma unroll
    for (int mi = 0; mi < 4; ++mi) {
        #pragma unroll
        for (int rr = 0; rr < 4; ++rr) {
            const int row = rbase + mi * 16 + rr;
            #pragma unroll
            for (int ni = 0; ni < 4; ++ni) {
                const int c = col0 + ni * 16;
                float v = acc[mi][ni][rr];
                if (MODE == 2) {
                    float uu = __bfloat162float(U[(size_t)row * H_DIM + c]);
                    __builtin_nontemporal_store(v + uu * Dvec[c],
                                                &OutF[(size_t)row * N + c]);
                } else {
                    OutBF[(size_t)row * N + c] = __float2bfloat16(v);
                }
            }
        }
    }

    if (MODE == 1) {
        // ---- fused phase1: agg_cg(p) = sum_t lam_p^(63-t) * Bu_t(p) ----
        // Wave owns exactly one 64-row chunk. t = mi*16 + kq*4 + rr;
        // register-only weights: w starts at lam^(12-4kq), *= lam per
        // t-step, *= lam^12 between mi groups. Even lane holds re, odd
        // lane im (interleaved cols).
        const int par = fr & 1;
        const int cg  = (bm + wm) >> 6;
        #pragma unroll
        for (int ni = 0; ni < 4; ++ni) {
            const int ql = (wn + ni * 16 + (fr & ~1)) >> 1;   // 0..127
            const float2 lb = lam[(bn >> 1) + ql];
            const float l1r = lb.x, l1i = lb.y;
            const float l2r = l1r * l1r - l1i * l1i, l2i = 2.f * l1r * l1i;
            const float l4r = l2r * l2r - l2i * l2i, l4i = 2.f * l2r * l2i;
            const float l8r = l4r * l4r - l4i * l4i, l8i = 2.f * l4r * l4i;
            const float l12r = l8r * l4r - l8i * l4i;
            const float l12i = l8r * l4i + l8i * l4r;
            float wr_, wi_;                     // lam^(12-4kq)
            if      (kq == 0) { wr_ = l12r; wi_ = l12i; }
            else if (kq == 1) { wr_ = l8r;  wi_ = l8i;  }
            else if (kq == 2) { wr_ = l4r;  wi_ = l4i;  }
            else              { wr_ = 1.f;  wi_ = 0.f;  }
            float s = 0.f;
            #pragma unroll
            for (int mi2 = 3; mi2 >= 0; --mi2) {
                #pragma unroll
                for (int rr = 3; rr >= 0; --rr) {
                    float own  = acc[mi2][ni][rr];
                    float part = __shfl_xor(own, 1);
                    s += wr_ * own + (par ? wi_ : -wi_) * part;
                    float nr = wr_ * l1r - wi_ * l1i;
                    float nI = wr_ * l1i + wi_ * l1r;
                    wr_ = nr; wi_ = nI;
                }
                float nr = wr_ * l12r - wi_ * l12i;
                float nI = wr_ * l12i + wi_ * l12r;
                wr_ = nr; wi_ = nI;
            }
            s += __shfl_xor(s, 16);             // reduce over kq
            s += __shfl_xor(s, 32);
            float other = __shfl_xor(s, 1);     // partner component
            if (kq == 0 && par == 0)
                aggp[(size_t)cg * P_DIM + (bn >> 1) + ql] = make_float2(s, other);
        }
    }
}

// ---------------------------------------------------------------- scan
// phase2: wave-parallel carries. 1 wave per state; lane j owns chunks 4j..4j+3.
__global__ void scan_phase2p(const float2* __restrict__ agg,
                             const float2* __restrict__ lamT,
                             float2* __restrict__ carry) {
    const int w = threadIdx.x >> 6;
    const int j = threadIdx.x & 63;
    const int p = blockIdx.x * 4 + w;
    const float2 A = lamT[p];                               // lam^64
    float b2r = A.x * A.x - A.y * A.y, b2i = 2.f * A.x * A.y;
    float Br = b2r * b2r - b2i * b2i, Bi = 2.f * b2r * b2i; // lam^256
    float2 a[4];
    #pragma unroll
    for (int k = 0; k < 4; ++k) a[k] = agg[(size_t)(4 * j + k) * P_DIM + p];
    float xr = 0.f, xi = 0.f;
    #pragma unroll
    for (int k = 0; k < 4; ++k) {
        float nr = A.x * xr - A.y * xi + a[k].x;
        float ni = A.x * xi + A.y * xr + a[k].y;
        xr = nr; xi = ni;
    }
    float cr = Br, ci = Bi, vr = xr, vi = xi;
    #pragma unroll
    for (int d = 1; d < 64; d <<= 1) {
        float pvr = __shfl_up(vr, d), pvi = __shfl_up(vi, d);
        float pcr = __shfl_up(cr, d), pci = __shfl_up(ci, d);
        if (j >= d) {
            float nvr = cr * pvr - ci * pvi + vr;
            float nvi = cr * pvi + ci * pvr + vi;
            float ncr = cr * pcr - ci * pci;
            float nci = cr * pci + ci * pcr;
            vr = nvr; vi = nvi; cr = ncr; ci = nci;
        }
    }
    float sr = __shfl_up(vr, 1), si = __shfl_up(vi, 1);     // exclusive seed
    if (j == 0) { sr = 0.f; si = 0.f; }
    #pragma unroll
    for (int k = 0; k < 4; ++k) {
        carry[(size_t)(4 * j + k) * P_DIM + p] = make_float2(sr, si);
        float nr = A.x * sr - A.y * si + a[k].x;
        float ni = A.x * si + A.y * sr + a[k].y;
        sr = nr; si = ni;
    }
}

__global__ void scan_phase3(uint32_t* __restrict__ BuX,             // in-place
                            const float2* __restrict__ lam,
                            const float2* __restrict__ carry) {
    const int p = blockIdx.y * 256 + threadIdx.x;
    const int c = blockIdx.x;
    const float2 lb = lam[p];
    const float2 c0 = carry[(size_t)c * P_DIM + p];
    float xr = c0.x, xi = c0.y;
    uint32_t* b = BuX + (size_t)c * TCH * P_DIM + p;
    #pragma unroll 4
    for (int j = 0; j < TCH; ++j) {
        uint32_t v = *b;
        float nr = lb.x * xr - lb.y * xi + lo_bf(v);
        float ni = lb.x * xi + lb.y * xr + hi_bf(v);
        xr = nr; xi = ni;
        *b = pack_bf(xr, xi);
        b += P_DIM;
    }
}

// ---------------------------------------------------------------- launch
extern "C" void kernel_launch(void* const* d_in, const int* in_sizes, int n_in,
                              void* d_out, int out_size, void* d_ws, size_t ws_size,
                              hipStream_t stream) {
    float* out = (float*)d_out;  // (L,H) fp32

    char* w = (char*)d_ws;
    w += 256;
    float2* lam   = (float2*)w;  w += (size_t)P_DIM * 8;
    float2* lamT  = (float2*)w;  w += (size_t)P_DIM * 8;
    float*  d_f   = (float*)w;   w += (size_t)H_DIM * 4;
    float2* agg   = (float2*)w;  w += (size_t)NCH * P_DIM * 8;       // 2 MB
    float2* carry = (float2*)w;  w += (size_t)NCH * P_DIM * 8;       // 2 MB
    bf16*   W1t   = (bf16*)w;    w += (size_t)2 * P_DIM * H_DIM * 2; // 4 MB
    bf16*   W2t   = (bf16*)w;    w += (size_t)H_DIM * 2 * P_DIM * 2; // 4 MB
    bf16*   ub    = (bf16*)w;    w += (size_t)L_SEQ * H_DIM * 2;     // 33.5 MB
    bf16*   Xbuf  = (bf16*)w;                                        // 67 MB

    convert_u<<<(L_SEQ * H_DIM / 8) / 256, 256, 0, stream>>>(d_in[0], ub);
    prep_all<<<P_DIM, 256, 0, stream>>>(d_in[0], d_in[1], d_in[2], d_in[6],
                                        d_in[3], d_in[4], d_in[5],
                                        W1t, W2t, d_f, lam, lamT);

    // Bu(L,2P) = ub @ W1t^T  (interleaved cols) + fused chunk aggregates
    gemm256<2 * P_DIM, H_DIM, 1><<<(2 * P_DIM / 256) * (L_SEQ / 256), 1024, 0, stream>>>(
        ub, W1t, Xbuf, nullptr, nullptr, nullptr, lam, agg);

    scan_phase2p<<<P_DIM / 4, 256, 0, stream>>>(agg, lamT, carry);
    scan_phase3<<<dim3(NCH, P_DIM / 256), 256, 0, stream>>>(
        (uint32_t*)Xbuf, lam, carry);

    // out = X @ W2t^T + ub*D
    gemm256<H_DIM, 2 * P_DIM, 2><<<(H_DIM / 256) * (L_SEQ / 256), 1024, 0, stream>>>(
        Xbuf, W2t, nullptr, out, ub, d_f, nullptr, nullptr);
}